// Round 9
// baseline (118.483 us; speedup 1.0000x reference)
//
#include <hip/hip_runtime.h>
#include <hip/hip_bf16.h>
#include <math.h>

#define BB 64
#define NN 1025
#define DD 768
#define HH 128
#define KK 256
#define TOK (BB*NN)          // 65600
#define OUT_XRED 0
#define OUT_IDX  (BB*(KK+1)*DD)            // 12,632,064
#define OUT_SC   (OUT_IDX + BB*(KK+1))     // + 16,448

typedef float    f32x4 __attribute__((ext_vector_type(4)));
typedef __fp16   h16x2 __attribute__((ext_vector_type(2)));
typedef _Float16 f16x8 __attribute__((ext_vector_type(8)));
#define NSTEP (DD/32)        // 24 MFMA k-steps

union U4F { uint4 u; f16x8 h; };
union H2U { h16x2 h; unsigned int u; };

// ---- K0: W1w = lnw ∘ W1 -> f16, MFMA-frag-transposed layout --------
// wt[((s*4+g)*HH + n)*8 + j] = f16(lnw[k] * W1[k][n]), k = s*32+g*8+j
__global__ __launch_bounds__(256) void k_cvtw(const float* __restrict__ w1,
                                              const float* __restrict__ lnw,
                                              unsigned short* __restrict__ wt)
{
    int i = blockIdx.x*256 + threadIdx.x;    // 98304 exact
    int k = i >> 7, n = i & 127;
    union { _Float16 h; unsigned short s; } c;
    c.h = (_Float16)(w1[i] * lnw[k]);
    int s = k >> 5, g = (k >> 3) & 3, j = k & 7;
    wt[((s*4 + g)*HH + n)*8 + j] = c.s;
}

// ---- K0b: c1[n] = lnb@W1 + b1, c2[n] = lnw@W1 (f32, 2x128) ---------
__global__ __launch_bounds__(128) void k_cvec(const float* __restrict__ w1,
                                              const float* __restrict__ lnw,
                                              const float* __restrict__ lnb,
                                              const float* __restrict__ b1,
                                              float* __restrict__ cvec)
{
    const int n = threadIdx.x;
    float s1 = 0.f, s2 = 0.f;
    #pragma unroll 8
    for (int k = 0; k < DD; ++k) {
        float wv = w1[k*HH + n];
        s1 = fmaf(lnb[k], wv, s1);
        s2 = fmaf(lnw[k], wv, s2);
    }
    cvec[n]      = s1 + b1[n];
    cvec[128+n]  = s2;
}

// ---- K_fused: stats + raw-f16 pack + MFMA + folded-LN epilogue -----
// 16 tokens/block, 4 waves, ~25 KB LDS -> 6 blocks/CU.
// Pass A: load x row (f32), f32 stats, pkrtz RAW x -> frag-ordered
// swizzled plane. lgkmcnt-only barrier (B prefetch stays in flight).
// Phase C: ds_read_b128 + 2 prefetched B loads + 2 MFMA per step.
// Epilogue: v = rs*acc + c1[col] - mu*rs*c2[col]; exact gelu; w2-dot.
__global__ __launch_bounds__(256, 6) void k_fused(const float* __restrict__ x,
    const unsigned short* __restrict__ wt,
    const float* __restrict__ cvec,
    const float* __restrict__ w2, const float* __restrict__ b2,
    float* __restrict__ scores_out)
{
    __shared__ uint4 planes[16*96];     // 24 KB, raw-x f16 plane
    __shared__ float mus[16], rss[16];
    __shared__ float part[4][16];

    const int tid  = threadIdx.x;
    const int wave = tid >> 6, lane = tid & 63;
    const int g    = lane >> 4, t16 = lane & 15;
    const int t7   = t16 & 7;
    const int tok0 = blockIdx.x * 16;     // grid 4100 exact
    const int colbase = wave * 32;
    const int row = tid >> 4, l16 = tid & 15;

    // ---- pass A: load row, f32 stats, pack raw x -> plane
    const float4* srow4 = reinterpret_cast<const float4*>(x + (size_t)(tok0 + row) * DD);
    const int rsz = row & 7;
    float s_ = 0.f, ss = 0.f;
    #pragma unroll
    for (int j = 0; j < 6; ++j) {
        float4 a = srow4[l16*2 + j*32];
        float4 b = srow4[l16*2 + j*32 + 1];
        s_ += ((a.x + a.y) + (a.z + a.w)) + ((b.x + b.y) + (b.z + b.w));
        ss += a.x*a.x + a.y*a.y + a.z*a.z + a.w*a.w
            + b.x*b.x + b.y*b.y + b.z*b.z + b.w*b.w;
        H2U h01, h23, h45, h67;
        h01.h = __builtin_amdgcn_cvt_pkrtz(a.x, a.y);
        h23.h = __builtin_amdgcn_cvt_pkrtz(a.z, a.w);
        h45.h = __builtin_amdgcn_cvt_pkrtz(b.x, b.y);
        h67.h = __builtin_amdgcn_cvt_pkrtz(b.z, b.w);
        planes[row*96 + ((l16 + j*16) ^ rsz)] = make_uint4(h01.u, h23.u, h45.u, h67.u);
    }
    #pragma unroll
    for (int m = 8; m; m >>= 1) { s_ += __shfl_xor(s_, m, 64); ss += __shfl_xor(ss, m, 64); }
    const float mu = s_ * (1.0f/768.0f);
    const float rs = 1.0f / sqrtf(ss * (1.0f/768.0f) - mu*mu + 1e-5f);
    if (l16 == 0) { mus[row] = mu; rss[row] = rs; }

    // ---- prefetch step-0 B fragments (stay in flight across barrier)
    const unsigned short* wtp = wt + ((size_t)g*HH + colbase + t16)*8;
    f16x8 nB0 = *reinterpret_cast<const f16x8*>(wtp);
    f16x8 nB1 = *reinterpret_cast<const f16x8*>(wtp + 128);

    // lgkmcnt-only barrier: LDS writes visible, VMEM (B) not drained
    asm volatile("s_waitcnt lgkmcnt(0)" ::: "memory");
    __builtin_amdgcn_s_barrier();

    // ---- phase C: fully-unrolled MFMA loop with rotating B prefetch
    f32x4 acc0 = {0,0,0,0}, acc1 = {0,0,0,0};
    #pragma unroll
    for (int s = 0; s < NSTEP; ++s) {
        f16x8 B0 = nB0, B1 = nB1;
        if (s + 1 < NSTEP) {
            nB0 = *reinterpret_cast<const f16x8*>(wtp + (size_t)(s+1)*4096);
            nB1 = *reinterpret_cast<const f16x8*>(wtp + (size_t)(s+1)*4096 + 128);
        }
        U4F Ah;
        Ah.u = planes[((s*4 + g) ^ t7) + t16*96];
        acc0 = __builtin_amdgcn_mfma_f32_16x16x32_f16(Ah.h, B0, acc0, 0, 0, 0);
        acc1 = __builtin_amdgcn_mfma_f32_16x16x32_f16(Ah.h, B1, acc1, 0, 0, 0);
    }

    // ---- epilogue: folded LN + exact gelu (f32) + w2-dot + reduce
    const int c0 = colbase + t16, c1i = colbase + 16 + t16;
    const float c1A = cvec[c0],      c2A = cvec[128 + c0];
    const float c1B = cvec[c1i],     c2B = cvec[128 + c1i];
    const float w2A = w2[c0],        w2B = w2[c1i];
    const float is2 = 0.70710678f;

    float psum[4];
    #pragma unroll
    for (int r = 0; r < 4; ++r) {
        const float mur = mus[g*4 + r], rsr = rss[g*4 + r];
        float v0 = rsr*acc0[r] + c1A - mur*rsr*c2A;
        float v1 = rsr*acc1[r] + c1B - mur*rsr*c2B;
        float g0 = 0.5f * v0 * (1.0f + erff(v0 * is2));
        float g1 = 0.5f * v1 * (1.0f + erff(v1 * is2));
        float p = g0 * w2A + g1 * w2B;
        #pragma unroll
        for (int m = 8; m; m >>= 1) p += __shfl_xor(p, m, 64);
        psum[r] = p;
    }
    if (t16 == 0) {
        #pragma unroll
        for (int r = 0; r < 4; ++r) part[wave][g*4 + r] = psum[r];
    }
    __syncthreads();
    if (tid < 16) {
        float s = part[0][tid] + part[1][tid] + part[2][tid] + part[3][tid] + b2[0];
        int tok = tok0 + tid;
        scores_out[tok] = ((tok % NN) == 0) ? 1.0e9f : s;
    }
}

// ---- K3: per-batch bitonic top-k + fused gather --------------------
__global__ __launch_bounds__(1024) void k_topk_gather(const float* __restrict__ scores,
                                                      const float* __restrict__ x,
                                                      float* __restrict__ idx_out,
                                                      float* __restrict__ xred)
{
    __shared__ float sk_[1024];
    __shared__ int   si[1024];
    const int tid = threadIdx.x;
    const int b   = blockIdx.x;
    sk_[tid] = scores[b*NN + 1 + tid];
    si[tid] = tid + 1;
    __syncthreads();
    for (int k = 2; k <= 1024; k <<= 1) {
        for (int j = k >> 1; j > 0; j >>= 1) {
            int ixj = tid ^ j;
            if (ixj > tid) {
                float sa = sk_[tid]; int ia = si[tid];
                float sb = sk_[ixj]; int ib = si[ixj];
                bool beforeB = (sb > sa) || (sb == sa && ib < ia);
                bool dirAsc  = ((tid & k) == 0);
                if (beforeB == dirAsc) {
                    sk_[tid] = sb; si[tid] = ib;
                    sk_[ixj] = sa; si[ixj] = ia;
                }
            }
            __syncthreads();
        }
    }
    if (tid == 0)  idx_out[b*(KK+1)] = 0.0f;
    if (tid < KK)  idx_out[b*(KK+1) + 1 + tid] = (float)si[tid];

    // fused gather: 257 rows x 192 float4 per batch
    const float4* xb4 = reinterpret_cast<const float4*>(x + (size_t)b*NN*DD);
    float4* dst4 = reinterpret_cast<float4*>(xred + (size_t)b*(KK+1)*DD);
    for (int i = tid; i < (KK+1)*192; i += 1024) {
        int r = i / 192, c = i - r*192;
        int idx = (r == 0) ? 0 : si[r-1];
        dst4[i] = xb4[idx*192 + c];
    }
}

extern "C" void kernel_launch(void* const* d_in, const int* in_sizes, int n_in,
                              void* d_out, int out_size, void* d_ws, size_t ws_size,
                              hipStream_t stream)
{
    const float* x   = (const float*)d_in[0];
    const float* lnw = (const float*)d_in[1];
    const float* lnb = (const float*)d_in[2];
    const float* w1  = (const float*)d_in[3];
    const float* b1  = (const float*)d_in[4];
    const float* w2  = (const float*)d_in[5];
    const float* b2  = (const float*)d_in[6];

    float* out   = (float*)d_out;
    float* xred  = out + OUT_XRED;
    float* idxf  = out + OUT_IDX;
    float* scout = out + OUT_SC;

    unsigned short* wt = (unsigned short*)d_ws;           // 196,608 B
    float* cvec = (float*)((char*)d_ws + 196608);         // 1,024 B

    k_cvtw <<<DD*HH/256, 256, 0, stream>>>(w1, lnw, wt);
    k_cvec <<<1, 128, 0, stream>>>(w1, lnw, lnb, b1, cvec);
    k_fused<<<TOK/16, 256, 0, stream>>>(x, wt, cvec, w2, b2, scout);
    k_topk_gather<<<BB, 1024, 0, stream>>>(scout, x, idxf, xred);
}

// Round 10
// 95.338 us; speedup vs baseline: 1.2428x; 1.2428x over previous
//
#include <hip/hip_runtime.h>
#include <hip/hip_bf16.h>
#include <math.h>

#define BB 64
#define NN 1025
#define DD 768
#define HH 128
#define KK 256
#define TOK (BB*NN)          // 65600
#define OUT_XRED 0
#define OUT_IDX  (BB*(KK+1)*DD)            // 12,632,064
#define OUT_SC   (OUT_IDX + BB*(KK+1))     // + 16,448

typedef float    f32x4 __attribute__((ext_vector_type(4)));
typedef __fp16   h16x2 __attribute__((ext_vector_type(2)));
typedef _Float16 f16x8 __attribute__((ext_vector_type(8)));
#define NSTEP (DD/32)        // 24 MFMA k-steps

union U4F { uint4 u; f16x8 h; };
union H2U { h16x2 h; unsigned int u; };

// ---- K0: W1w = lnw ∘ W1 -> f16, MFMA-frag-transposed layout --------
// wt[((s*4+g)*HH + n)*8 + j] = f16(lnw[k] * W1[k][n]), k = s*32+g*8+j
__global__ __launch_bounds__(256) void k_cvtw(const float* __restrict__ w1,
                                              const float* __restrict__ lnw,
                                              unsigned short* __restrict__ wt)
{
    int i = blockIdx.x*256 + threadIdx.x;    // 98304 exact
    int k = i >> 7, n = i & 127;
    union { _Float16 h; unsigned short s; } c;
    c.h = (_Float16)(w1[i] * lnw[k]);
    int s = k >> 5, g = (k >> 3) & 3, j = k & 7;
    wt[((s*4 + g)*HH + n)*8 + j] = c.s;
}

// ---- K0b: c1[n] = lnb@W1 + b1, c2[n] = lnw@W1 ----------------------
// 1 block x 1024 threads = 8 rows x 128 cols, coalesced, LDS reduce.
__global__ __launch_bounds__(1024) void k_cvec(const float* __restrict__ w1,
                                               const float* __restrict__ lnw,
                                               const float* __restrict__ lnb,
                                               const float* __restrict__ b1,
                                               float* __restrict__ cvec)
{
    __shared__ float red[2][8][128];
    const int n = threadIdx.x & 127;
    const int r = threadIdx.x >> 7;          // 0..7
    float s1 = 0.f, s2 = 0.f;
    #pragma unroll 8
    for (int j = 0; j < 96; ++j) {
        int k = r + j*8;
        float wv = w1[k*HH + n];
        s1 = fmaf(lnb[k], wv, s1);
        s2 = fmaf(lnw[k], wv, s2);
    }
    red[0][r][n] = s1;
    red[1][r][n] = s2;
    __syncthreads();
    if (r == 0) {
        float t1 = 0.f, t2 = 0.f;
        #pragma unroll
        for (int q = 0; q < 8; ++q) { t1 += red[0][q][n]; t2 += red[1][q][n]; }
        cvec[n]     = t1 + b1[n];
        cvec[128+n] = t2;
    }
}

// ---- K_fused: stats + raw-f16 pack + MFMA + folded-LN epilogue -----
// 16 tokens/block, 4 waves, ~25 KB LDS -> 6 blocks/CU (LDS-capped).
__global__ __launch_bounds__(256) void k_fused(const float* __restrict__ x,
    const unsigned short* __restrict__ wt,
    const float* __restrict__ cvec,
    const float* __restrict__ w2, const float* __restrict__ b2,
    float* __restrict__ scores_out)
{
    __shared__ uint4 planes[16*96];     // 24 KB, raw-x f16 plane
    __shared__ float mus[16], rss[16];
    __shared__ float part[4][16];

    const int tid  = threadIdx.x;
    const int wave = tid >> 6, lane = tid & 63;
    const int g    = lane >> 4, t16 = lane & 15;
    const int t7   = t16 & 7;
    const int tok0 = blockIdx.x * 16;     // grid 4100 exact
    const int colbase = wave * 32;
    const int row = tid >> 4, l16 = tid & 15;

    // ---- pass A: load row, f32 stats, pack raw x -> plane
    const float4* srow4 = reinterpret_cast<const float4*>(x + (size_t)(tok0 + row) * DD);
    const int rsz = row & 7;
    float s_ = 0.f, ss = 0.f;
    #pragma unroll
    for (int j = 0; j < 6; ++j) {
        float4 a = srow4[l16*2 + j*32];
        float4 b = srow4[l16*2 + j*32 + 1];
        s_ += ((a.x + a.y) + (a.z + a.w)) + ((b.x + b.y) + (b.z + b.w));
        ss += a.x*a.x + a.y*a.y + a.z*a.z + a.w*a.w
            + b.x*b.x + b.y*b.y + b.z*b.z + b.w*b.w;
        H2U h01, h23, h45, h67;
        h01.h = __builtin_amdgcn_cvt_pkrtz(a.x, a.y);
        h23.h = __builtin_amdgcn_cvt_pkrtz(a.z, a.w);
        h45.h = __builtin_amdgcn_cvt_pkrtz(b.x, b.y);
        h67.h = __builtin_amdgcn_cvt_pkrtz(b.z, b.w);
        planes[row*96 + ((l16 + j*16) ^ rsz)] = make_uint4(h01.u, h23.u, h45.u, h67.u);
    }
    #pragma unroll
    for (int m = 8; m; m >>= 1) { s_ += __shfl_xor(s_, m, 64); ss += __shfl_xor(ss, m, 64); }
    const float mu = s_ * (1.0f/768.0f);
    const float rs = 1.0f / sqrtf(ss * (1.0f/768.0f) - mu*mu + 1e-5f);
    if (l16 == 0) { mus[row] = mu; rss[row] = rs; }

    // ---- prefetch step-0 B fragments (stay in flight across barrier)
    const unsigned short* wtp = wt + ((size_t)g*HH + colbase + t16)*8;
    f16x8 nB0 = *reinterpret_cast<const f16x8*>(wtp);
    f16x8 nB1 = *reinterpret_cast<const f16x8*>(wtp + 128);

    // lgkmcnt-only barrier: LDS writes visible, VMEM (B) not drained
    asm volatile("s_waitcnt lgkmcnt(0)" ::: "memory");
    __builtin_amdgcn_s_barrier();

    // ---- phase C: fully-unrolled MFMA loop with rotating B prefetch
    f32x4 acc0 = {0,0,0,0}, acc1 = {0,0,0,0};
    #pragma unroll
    for (int s = 0; s < NSTEP; ++s) {
        f16x8 B0 = nB0, B1 = nB1;
        if (s + 1 < NSTEP) {
            nB0 = *reinterpret_cast<const f16x8*>(wtp + (size_t)(s+1)*4096);
            nB1 = *reinterpret_cast<const f16x8*>(wtp + (size_t)(s+1)*4096 + 128);
        }
        U4F Ah;
        Ah.u = planes[((s*4 + g) ^ t7) + t16*96];
        acc0 = __builtin_amdgcn_mfma_f32_16x16x32_f16(Ah.h, B0, acc0, 0, 0, 0);
        acc1 = __builtin_amdgcn_mfma_f32_16x16x32_f16(Ah.h, B1, acc1, 0, 0, 0);
    }

    // ---- epilogue: folded LN + exact gelu (f32) + w2-dot + reduce
    const int c0 = colbase + t16, c1i = colbase + 16 + t16;
    const float c1A = cvec[c0],      c2A = cvec[128 + c0];
    const float c1B = cvec[c1i],     c2B = cvec[128 + c1i];
    const float w2A = w2[c0],        w2B = w2[c1i];
    const float is2 = 0.70710678f;

    float psum[4];
    #pragma unroll
    for (int r = 0; r < 4; ++r) {
        const float mur = mus[g*4 + r], rsr = rss[g*4 + r];
        float v0 = rsr*acc0[r] + c1A - mur*rsr*c2A;
        float v1 = rsr*acc1[r] + c1B - mur*rsr*c2B;
        float g0 = 0.5f * v0 * (1.0f + erff(v0 * is2));
        float g1 = 0.5f * v1 * (1.0f + erff(v1 * is2));
        float p = g0 * w2A + g1 * w2B;
        #pragma unroll
        for (int m = 8; m; m >>= 1) p += __shfl_xor(p, m, 64);
        psum[r] = p;
    }
    if (t16 == 0) {
        #pragma unroll
        for (int r = 0; r < 4; ++r) part[wave][g*4 + r] = psum[r];
    }
    __syncthreads();
    if (tid < 16) {
        float s = part[0][tid] + part[1][tid] + part[2][tid] + part[3][tid] + b2[0];
        int tok = tok0 + tid;
        scores_out[tok] = ((tok % NN) == 0) ? 1.0e9f : s;
    }
}

// ---- K3: per-batch bitonic top-k (full 1024 sort, f32) -------------
__global__ __launch_bounds__(1024) void k_topk(const float* __restrict__ scores,
                                               float* __restrict__ idx_out)
{
    __shared__ float sk_[1024];
    __shared__ int   si[1024];
    const int tid = threadIdx.x;
    const int b   = blockIdx.x;
    sk_[tid] = scores[b*NN + 1 + tid];
    si[tid] = tid + 1;
    __syncthreads();
    for (int k = 2; k <= 1024; k <<= 1) {
        for (int j = k >> 1; j > 0; j >>= 1) {
            int ixj = tid ^ j;
            if (ixj > tid) {
                float sa = sk_[tid]; int ia = si[tid];
                float sb = sk_[ixj]; int ib = si[ixj];
                bool beforeB = (sb > sa) || (sb == sa && ib < ia);
                bool dirAsc  = ((tid & k) == 0);
                if (beforeB == dirAsc) {
                    sk_[tid] = sb; si[tid] = ib;
                    sk_[ixj] = sa; si[ixj] = ia;
                }
            }
            __syncthreads();
        }
    }
    if (tid == 0)  idx_out[b*(KK+1)] = 0.0f;
    if (tid < KK)  idx_out[b*(KK+1) + 1 + tid] = (float)si[tid];
}

// ---- K4: gather selected tokens (wide grid, streaming) -------------
__global__ __launch_bounds__(192) void k_gather(const float* __restrict__ x,
                                                const float* __restrict__ idx_out,
                                                float* __restrict__ xred)
{
    const int r = blockIdx.x;               // 0 .. 64*257-1
    const int b = r / (KK+1);
    const int idx = (int)(idx_out[r] + 0.5f);
    const float4* src = reinterpret_cast<const float4*>(x + ((size_t)b*NN + idx) * DD);
    float4* dst = reinterpret_cast<float4*>(xred + (size_t)r * DD);
    dst[threadIdx.x] = src[threadIdx.x];
}

extern "C" void kernel_launch(void* const* d_in, const int* in_sizes, int n_in,
                              void* d_out, int out_size, void* d_ws, size_t ws_size,
                              hipStream_t stream)
{
    const float* x   = (const float*)d_in[0];
    const float* lnw = (const float*)d_in[1];
    const float* lnb = (const float*)d_in[2];
    const float* w1  = (const float*)d_in[3];
    const float* b1  = (const float*)d_in[4];
    const float* w2  = (const float*)d_in[5];
    const float* b2  = (const float*)d_in[6];

    float* out   = (float*)d_out;
    float* xred  = out + OUT_XRED;
    float* idxf  = out + OUT_IDX;
    float* scout = out + OUT_SC;

    unsigned short* wt = (unsigned short*)d_ws;           // 196,608 B
    float* cvec = (float*)((char*)d_ws + 196608);         // 1,024 B

    k_cvtw <<<DD*HH/256, 256, 0, stream>>>(w1, lnw, wt);
    k_cvec <<<1, 1024, 0, stream>>>(w1, lnw, lnb, b1, cvec);
    k_fused<<<TOK/16, 256, 0, stream>>>(x, wt, cvec, w2, b2, scout);
    k_topk <<<BB, 1024, 0, stream>>>(scout, idxf);
    k_gather<<<BB*(KK+1), 192, 0, stream>>>(x, idxf, xred);
}